// Round 6
// baseline (454.956 us; speedup 1.0000x reference)
//
#include <hip/hip_runtime.h>

#define B_SZ 2
#define L_SEQ 2048
#define E_DIM 1024
#define NH 16
#define DH 64
#define DFF_DIM 4096
#define ROWS (B_SZ * L_SEQ)  // 4096
#define NCID 80              // KV chunks per (b,h): sum ceil((qt+1)/8), qt<32

typedef __attribute__((ext_vector_type(8))) short short8;
typedef __attribute__((ext_vector_type(4))) float f32x4;

// ---- bf16 <-> f32 helpers ----
__device__ __forceinline__ short f2bf(float f) {
  unsigned u = __builtin_bit_cast(unsigned, f);
  u = (u + 0x7FFFu + ((u >> 16) & 1u)) >> 16;
  return (short)u;
}
__device__ __forceinline__ float bf2f(short s) {
  unsigned u = ((unsigned)(unsigned short)s) << 16;
  return __builtin_bit_cast(float, u);
}

// ---- async global->LDS 16B copy ----
__device__ __forceinline__ void async_copy16(const void* g, void* l) {
  __builtin_amdgcn_global_load_lds(
      (const __attribute__((address_space(1))) void*)g,
      (__attribute__((address_space(3))) void*)l, 16, 0, 0);
}

// ---- block reduction over 256 threads (4 waves) ----
__device__ __forceinline__ float block_sum256(float v) {
  __shared__ float sbuf[4];
#pragma unroll
  for (int off = 32; off > 0; off >>= 1) v += __shfl_xor(v, off, 64);
  int lane = threadIdx.x & 63, w = threadIdx.x >> 6;
  if (lane == 0) sbuf[w] = v;
  __syncthreads();
  return sbuf[0] + sbuf[1] + sbuf[2] + sbuf[3];
}

// ---- fused prep: weight transposes (with QKV head-split remap) + rmsnorm ----
__global__ __launch_bounds__(256) void prep_all(
    const float* __restrict__ Wqkv, const float* __restrict__ Wo,
    const float* __restrict__ Ww, const float* __restrict__ Wv,
    const float* __restrict__ Wout, const float* __restrict__ X,
    short* __restrict__ WqkT, short* __restrict__ Wv3T,
    short* __restrict__ WoT, short* __restrict__ Bcat,
    short* __restrict__ WoutT, short* __restrict__ H) {
  __shared__ float tile[32][33];
  int b = blockIdx.x;
  if (b < 16384) {
    const float* W;
    int K, N, mode, bx, by;  // mode: 0=qkv-split 1=plain 2=Bcat+0 3=Bcat+64
    short* Wt;
    if (b < 3072) {
      W = Wqkv; Wt = nullptr; K = 1024; N = 3072; mode = 0;
      bx = b % 96; by = b / 96;
    } else if (b < 4096) {
      int c = b - 3072;
      W = Wo; Wt = WoT; K = 1024; N = 1024; mode = 1;
      bx = c & 31; by = c >> 5;
    } else if (b < 8192) {
      int c = b - 4096;
      W = Ww; Wt = Bcat; K = 1024; N = 4096; mode = 2;
      bx = c & 127; by = c >> 7;
    } else if (b < 12288) {
      int c = b - 8192;
      W = Wv; Wt = Bcat; K = 1024; N = 4096; mode = 3;
      bx = c & 127; by = c >> 7;
    } else {
      int c = b - 12288;
      W = Wout; Wt = WoutT; K = 4096; N = 1024; mode = 1;
      bx = c & 31; by = c >> 5;
    }
    int n0 = bx * 32, k0 = by * 32;
    int tx = threadIdx.x & 31, ty = threadIdx.x >> 5;
#pragma unroll
    for (int i = 0; i < 4; i++)
      tile[ty + 8 * i][tx] = W[(size_t)(k0 + ty + 8 * i) * N + n0 + tx];
    __syncthreads();
#pragma unroll
    for (int i = 0; i < 4; i++) {
      int n = n0 + ty + 8 * i;
      short val = f2bf(tile[tx][ty + 8 * i]);
      if (mode == 0) {
        int h = n / 192, rem = n - h * 192;
        if (rem < 128)
          WqkT[(size_t)(h * 128 + rem) * 1024 + k0 + tx] = val;
        else
          Wv3T[(size_t)(h * 64 + rem - 128) * 1024 + k0 + tx] = val;
      } else {
        int orow = (mode == 1) ? n
                               : ((n >> 6) * 128 + (n & 63) + (mode == 3 ? 64 : 0));
        Wt[(size_t)orow * K + k0 + tx] = val;
      }
    }
  } else {
    size_t row = b - 16384;
    float4 v = ((const float4*)(X + row * E_DIM))[threadIdx.x];
    float ss = v.x * v.x + v.y * v.y + v.z * v.z + v.w * v.w;
    ss = block_sum256(ss);
    float inv = rsqrtf(ss * (1.0f / E_DIM));
    short* h = H + row * E_DIM + (size_t)threadIdx.x * 4;
    h[0] = f2bf(v.x * inv);
    h[1] = f2bf(v.y * inv);
    h[2] = f2bf(v.z * inv);
    h[3] = f2bf(v.w * inv);
  }
}

// ---- fused: X1 = X + p0 + p1 + bias; X2 = X1*(1+1/rms) -> Xout; h2 -> H ----
__global__ __launch_bounds__(256) void resid_rms_fused(
    const float* __restrict__ X, const float* __restrict__ P0,
    const float* __restrict__ P1, const float* __restrict__ bias,
    float* __restrict__ Xout, short* __restrict__ H) {
  size_t row = blockIdx.x;
  int t = threadIdx.x;
  float4 v = ((const float4*)(X + row * E_DIM))[t];
  float4 a = ((const float4*)(P0 + row * E_DIM))[t];
  float4 b = ((const float4*)(P1 + row * E_DIM))[t];
  float4 c = ((const float4*)bias)[t];
  v.x += a.x + b.x + c.x;
  v.y += a.y + b.y + c.y;
  v.z += a.z + b.z + c.z;
  v.w += a.w + b.w + c.w;
  float ss = v.x * v.x + v.y * v.y + v.z * v.z + v.w * v.w;
  ss = block_sum256(ss);
  float inv = rsqrtf(ss * (1.0f / E_DIM));
  float4 o;
  o.x = v.x * (1.0f + inv);
  o.y = v.y * (1.0f + inv);
  o.z = v.z * (1.0f + inv);
  o.w = v.w * (1.0f + inv);
  ((float4*)(Xout + row * E_DIM))[t] = o;
  short* h = H + row * E_DIM + (size_t)t * 4;
  h[0] = f2bf(v.x * inv);
  h[1] = f2bf(v.y * inv);
  h[2] = f2bf(v.z * inv);
  h[3] = f2bf(v.w * inv);
}

// ---- GEMM: C(MxN) = A(MxK bf16) @ Bt(NxK bf16)^T, BK=64 twin buffers ----
// epi: 4 = f32 partial (split-K z), 5 = gated-FFN, 6 = QK scatter (out=Qh,
// out2=Kh, bias=bqkv), 7 = V^T scatter (out=VTh, bias=bqkv by row),
// 8 = atomicAdd f32 into out (split-K z over K halves)
__global__ __launch_bounds__(256, 2) void gemm_bt(
    const short* __restrict__ A, const short* __restrict__ Bt,
    const float* __restrict__ bias, void* __restrict__ out,
    void* __restrict__ out2, int M, int N, int K, int epi, int ksplit) {
  __shared__ short smem[128 * 32 * 4];  // As0 Bs0 As1 Bs1 = 32 KB
  short* As0 = smem;
  short* Bs0 = smem + 4096;
  short* As1 = smem + 8192;
  short* Bs1 = smem + 12288;
  int t = threadIdx.x;
  int lane = t & 63;
  int quad = lane >> 4, l16 = lane & 15;
  int wave = t >> 6;
  int wr = wave >> 1, wc = wave & 1;
  int m0 = blockIdx.y * 128, n0 = blockIdx.x * 128;
  int klen = K / ksplit;
  int kstart = blockIdx.z * klen;

  f32x4 acc[4][4];
#pragma unroll
  for (int i = 0; i < 4; i++)
#pragma unroll
    for (int j = 0; j < 4; j++) acc[i][j] = (f32x4){0.f, 0.f, 0.f, 0.f};

  for (int k0 = kstart; k0 < kstart + klen; k0 += 64) {
    __syncthreads();
#pragma unroll
    for (int p = 0; p < 2; p++) {
      int s = p * 256 + t;
      int mm = s >> 2, kk = (s & 3) * 8;
      const short* ag = A + (size_t)(m0 + mm) * K + k0 + kk;
      const short* bg = Bt + (size_t)(n0 + mm) * K + k0 + kk;
      async_copy16(ag, As0 + (size_t)s * 8);
      async_copy16(bg, Bs0 + (size_t)s * 8);
      async_copy16(ag + 32, As1 + (size_t)s * 8);
      async_copy16(bg + 32, Bs1 + (size_t)s * 8);
    }
    __syncthreads();
#pragma unroll
    for (int half = 0; half < 2; half++) {
      const short* As = half ? As1 : As0;
      const short* Bs = half ? Bs1 : Bs0;
      short8 af[4], bfv[4];
#pragma unroll
      for (int i = 0; i < 4; i++) {
        af[i] = *(const short8*)&As[(wr * 64 + i * 16 + l16) * 32 + quad * 8];
        bfv[i] = *(const short8*)&Bs[(wc * 64 + i * 16 + l16) * 32 + quad * 8];
      }
#pragma unroll
      for (int mi = 0; mi < 4; mi++)
#pragma unroll
        for (int ni = 0; ni < 4; ni++)
          acc[mi][ni] = __builtin_amdgcn_mfma_f32_16x16x32_bf16(
              af[mi], bfv[ni], acc[mi][ni], 0, 0, 0);
    }
  }

  if (epi == 5) {
    __syncthreads();
    short* xbuf = smem;  // 128 rows x 64 cols, stride 68
    if (wc == 0) {
#pragma unroll
      for (int mi = 0; mi < 4; mi++)
#pragma unroll
        for (int ni = 0; ni < 4; ni++)
#pragma unroll
          for (int r = 0; r < 4; r++) {
            int rowl = wr * 64 + mi * 16 + quad * 4 + r;
            float v = acc[mi][ni][r];
            float g = 0.5f * v * (1.0f + erff(v * 0.70710678118654752f));
            xbuf[rowl * 68 + ni * 16 + l16] = f2bf(g);
          }
    }
    __syncthreads();
    if (wc == 1) {
      short* FF = (short*)out;
#pragma unroll
      for (int mi = 0; mi < 4; mi++)
#pragma unroll
        for (int ni = 0; ni < 4; ni++)
#pragma unroll
          for (int r = 0; r < 4; r++) {
            int rowl = wr * 64 + mi * 16 + quad * 4 + r;
            int coll = ni * 16 + l16;
            float w = bf2f(xbuf[rowl * 68 + coll]);
            FF[(size_t)(m0 + rowl) * DFF_DIM + blockIdx.x * 64 + coll] =
                f2bf(w * acc[mi][ni][r]);
          }
    }
    return;
  }

#pragma unroll
  for (int mi = 0; mi < 4; mi++) {
#pragma unroll
    for (int ni = 0; ni < 4; ni++) {
      int col = n0 + wc * 64 + ni * 16 + l16;
#pragma unroll
      for (int r = 0; r < 4; r++) {
        int row = m0 + wr * 64 + mi * 16 + quad * 4 + r;
        float v = acc[mi][ni][r];
        if (epi == 4) {
          float* po = (float*)out + (size_t)blockIdx.z * ((size_t)M * N);
          po[(size_t)row * N + col] = v;
        } else if (epi == 6) {
          // row = global token, col = h*128 + t*64 + d
          v += bias[(col >> 7) * 192 + (col & 127)];
          int h = col >> 7, d = col & 63;
          short* dst = ((col >> 6) & 1) ? (short*)out2 : (short*)out;
          int bb = row >> 11, l = row & 2047;
          dst[((size_t)(bb * NH + h) * L_SEQ + l) * DH + d] = f2bf(v);
        } else if (epi == 7) {
          // row = h*64+d, col = global token -> VTh[bh][d][l]
          v += bias[(row >> 6) * 192 + 128 + (row & 63)];
          int bb = col >> 11, l = col & 2047;
          ((short*)out)[((size_t)(bb * NH + (row >> 6)) * DH + (row & 63)) *
                            L_SEQ +
                        l] = f2bf(v);
        } else {  // epi == 8: atomic accumulate (final output)
          unsafeAtomicAdd((float*)out + (size_t)row * N + col, v);
        }
      }
    }
  }
}

// ---- flash attention, constant-m softmax, split-KV (8-tile chunks) ----
__global__ __launch_bounds__(256) void attn_k(const short* __restrict__ Qh,
                                              const short* __restrict__ Kh,
                                              const short* __restrict__ VTh,
                                              float* __restrict__ OP,
                                              float* __restrict__ RS) {
  int cid = blockIdx.x;  // 0..79 flat (qt, chunk) id
  int bh = blockIdx.y;
  int b = bh >> 4, h = bh & 15;
  int qt, ch;
  if (cid < 8) {
    qt = cid; ch = 0;
  } else if (cid < 24) {
    qt = 8 + ((cid - 8) >> 1); ch = (cid - 8) & 1;
  } else if (cid < 48) {
    qt = 16 + (cid - 24) / 3; ch = (cid - 24) % 3;
  } else {
    qt = 24 + ((cid - 48) >> 2); ch = (cid - 48) & 3;
  }
  int t0 = ch * 8;
  int tend = min(t0 + 8, qt + 1);

  int t = threadIdx.x;
  int wave = t >> 6, lane = t & 63;
  int quad = lane >> 4, l16 = lane & 15;

  __shared__ short kt[64 * 72];
  __shared__ short vt[64 * 72];
  __shared__ short pb[4 * 16 * 70];

  const float slope = exp2f(-(1.0f + (7.0f / 15.0f) * (float)h));
  int iw = qt * 64 + wave * 16;

  short8 qf[2];
  {
    const short* qp = Qh + ((size_t)bh * L_SEQ + iw + l16) * DH + quad * 8;
    qf[0] = *(const short8*)(qp);
    qf[1] = *(const short8*)(qp + 32);
  }

  f32x4 o[4];
#pragma unroll
  for (int i = 0; i < 4; i++) o[i] = (f32x4){0.f, 0.f, 0.f, 0.f};
  float rs[4] = {0.f, 0.f, 0.f, 0.f};
  float crow[4];
  int irow[4];
#pragma unroll
  for (int r = 0; r < 4; r++) {
    irow[r] = iw + quad * 4 + r;
    crow[r] = -slope * (float)irow[r] - 8.0f;
  }

  int sr = t >> 3, sc = (t & 7) * 8;
  const short* kg = Kh + (size_t)bh * L_SEQ * DH;
  const short* vg = VTh + (size_t)bh * DH * L_SEQ;
  short8 kreg[2], vreg[2];
  auto loadKV = [&](int j0) {
    kreg[0] = *(const short8*)(kg + (size_t)(j0 + sr) * DH + sc);
    kreg[1] = *(const short8*)(kg + (size_t)(j0 + sr + 32) * DH + sc);
    vreg[0] = *(const short8*)(vg + (size_t)sr * L_SEQ + j0 + sc);
    vreg[1] = *(const short8*)(vg + (size_t)(sr + 32) * L_SEQ + j0 + sc);
  };
  loadKV(t0 * 64);

  short* pw = &pb[wave * 16 * 70];
  for (int tix = t0; tix < tend; ++tix) {
    int j0 = tix * 64;
    __syncthreads();
    *(short8*)&kt[sr * 72 + sc] = kreg[0];
    *(short8*)&kt[(sr + 32) * 72 + sc] = kreg[1];
    *(short8*)&vt[sr * 72 + sc] = vreg[0];
    *(short8*)&vt[(sr + 32) * 72 + sc] = vreg[1];
    __syncthreads();
    if (tix + 1 < tend) loadKV(j0 + 64);

    f32x4 s[4];
#pragma unroll
    for (int nt = 0; nt < 4; nt++) {
      f32x4 a = (f32x4){0.f, 0.f, 0.f, 0.f};
#pragma unroll
      for (int ks = 0; ks < 2; ks++) {
        short8 bf =
            *(const short8*)&kt[(nt * 16 + l16) * 72 + ks * 32 + quad * 8];
        a = __builtin_amdgcn_mfma_f32_16x16x32_bf16(qf[ks], bf, a, 0, 0, 0);
      }
      s[nt] = a;
    }
    bool diag = (tix == qt);
#pragma unroll
    for (int nt = 0; nt < 4; nt++) {
      int j = j0 + nt * 16 + l16;
      float jb = slope * (float)j;
#pragma unroll
      for (int r = 0; r < 4; r++) {
        float v = __builtin_fmaf(s[nt][r], 0.125f, jb + crow[r]);
        if (diag && j > irow[r]) v = -1e30f;
        float p = __expf(v);
        rs[r] += p;
        pw[(quad * 4 + r) * 70 + nt * 16 + l16] = f2bf(p);
      }
    }
    short8 pf[2];
    pf[0] = *(const short8*)&pw[l16 * 70 + quad * 8];
    pf[1] = *(const short8*)&pw[l16 * 70 + 32 + quad * 8];
#pragma unroll
    for (int nt = 0; nt < 4; nt++) {
#pragma unroll
      for (int ks = 0; ks < 2; ks++) {
        short8 bv =
            *(const short8*)&vt[(nt * 16 + l16) * 72 + ks * 32 + quad * 8];
        o[nt] = __builtin_amdgcn_mfma_f32_16x16x32_bf16(pf[ks], bv, o[nt], 0,
                                                        0, 0);
      }
    }
  }
  float* op = OP + ((size_t)bh * NCID + cid) * 64 * 64;
  float* rsp = RS + ((size_t)bh * NCID + cid) * 64;
#pragma unroll
  for (int r = 0; r < 4; r++) {
#pragma unroll
    for (int off = 1; off < 16; off <<= 1) rs[r] += __shfl_xor(rs[r], off, 64);
    int rowl = wave * 16 + quad * 4 + r;
#pragma unroll
    for (int nt = 0; nt < 4; nt++) op[rowl * 64 + nt * 16 + l16] = o[nt][r];
    if (l16 == 0) rsp[rowl] = rs[r];
  }
}

// ---- merge split-KV partials: ctx = sum(O) / sum(l) -> bf16 ----
__global__ __launch_bounds__(256) void attn_merge(const float* __restrict__ OP,
                                                  const float* __restrict__ RS,
                                                  short* __restrict__ ctx) {
  int row = blockIdx.x;
  int b = row >> 11, i = row & 2047;
  int qt = i >> 6, rowin = i & 63;
  int base, nch;
  if (qt < 8) {
    base = qt; nch = 1;
  } else if (qt < 16) {
    base = 8 + 2 * (qt - 8); nch = 2;
  } else if (qt < 24) {
    base = 24 + 3 * (qt - 16); nch = 3;
  } else {
    base = 48 + 4 * (qt - 24); nch = 4;
  }
  int t = threadIdx.x;
  int col = t * 4;
  int h = col >> 6;
  int bh = b * NH + h;
  float4 o = {0.f, 0.f, 0.f, 0.f};
  float l = 0.f;
  for (int s = 0; s < nch; s++) {
    size_t cb = ((size_t)bh * NCID + base + s) * 64 + rowin;
    float4 v = *(const float4*)&OP[cb * 64 + (col & 63)];
    o.x += v.x;
    o.y += v.y;
    o.z += v.z;
    o.w += v.w;
    l += RS[cb];
  }
  float inv = 1.0f / l;
  short* dst = ctx + (size_t)row * (NH * DH) + col;
  dst[0] = f2bf(o.x * inv);
  dst[1] = f2bf(o.y * inv);
  dst[2] = f2bf(o.z * inv);
  dst[3] = f2bf(o.w * inv);
}

extern "C" void kernel_launch(void* const* d_in, const int* in_sizes, int n_in,
                              void* d_out, int out_size, void* d_ws,
                              size_t ws_size, hipStream_t stream) {
  const float* X = (const float*)d_in[0];
  const float* Wqkv = (const float*)d_in[2];
  const float* bqkv = (const float*)d_in[3];
  const float* Wo_sa = (const float*)d_in[4];
  const float* bo_sa = (const float*)d_in[5];
  const float* Ww = (const float*)d_in[12];
  const float* Wv = (const float*)d_in[13];
  const float* Wout = (const float*)d_in[14];

  char* ws = (char*)d_ws;
  auto take = [&](size_t bytes) {
    char* p = ws;
    ws += (bytes + 255) & ~(size_t)255;
    return p;
  };
  short* WqkT = (short*)take((size_t)2048 * 1024 * 2);          // 4 MB
  short* Wv3T = (short*)take((size_t)1024 * 1024 * 2);          // 2 MB
  short* WoT = (short*)take((size_t)E_DIM * E_DIM * 2);         // 2 MB
  short* Bcat = (short*)take((size_t)2 * DFF_DIM * E_DIM * 2);  // 16 MB
  short* WoutT = (short*)take((size_t)E_DIM * DFF_DIM * 2);     // 8 MB
  short* Hbuf = (short*)take((size_t)ROWS * E_DIM * 2);         // 8 MB
  short* Qh = (short*)take((size_t)ROWS * NH * DH * 2);         // 8 MB
  short* CTX = (short*)take((size_t)ROWS * NH * DH * 2);        // 8 MB
  short* KVb = (short*)take((size_t)2 * B_SZ * NH * L_SEQ * DH * 2);  // 16 MB
  char* big = take((size_t)48 * 1024 * 1024);  // X1-era + FF region, 48 MB
  short* Kh = KVb;
  short* VTh = KVb + (size_t)B_SZ * NH * L_SEQ * DH;
  // attention split-KV partials live in `big` (dead until merge consumes):
  float* OP = (float*)big;  // 40 MB
  float* RS = OP + (size_t)B_SZ * NH * NCID * 64 * 64;  // 0.64 MB
  // after merge: FF (32 MB) and Wo partials (32 MB) reuse big+16MB:
  short* FF = (short*)(big + (size_t)16 * 1024 * 1024);
  float* Pwo = (float*)FF;
  (void)ws_size;
  (void)in_sizes;
  (void)n_in;
  (void)out_size;

  dim3 blk(256);
  prep_all<<<16384 + ROWS, blk, 0, stream>>>(Wqkv, Wo_sa, Ww, Wv, Wout, X,
                                             WqkT, Wv3T, WoT, Bcat, WoutT,
                                             Hbuf);
  // Q/K gemm -> Qh, Kh (scatter epilogue), 512 blocks
  gemm_bt<<<dim3(2048 / 128, ROWS / 128), blk, 0, stream>>>(
      Hbuf, WqkT, bqkv, Qh, Kh, ROWS, 2048, 1024, 6, 1);
  // V^T gemm -> VTh (transposed scatter), 256 blocks
  gemm_bt<<<dim3(ROWS / 128, 1024 / 128), blk, 0, stream>>>(
      Wv3T, Hbuf, bqkv, VTh, nullptr, 1024, ROWS, 1024, 7, 1);
  attn_k<<<dim3(NCID, B_SZ * NH), blk, 0, stream>>>(Qh, Kh, VTh, OP, RS);
  attn_merge<<<ROWS, blk, 0, stream>>>(OP, RS, CTX);
  // Wo partials, split-K=2 (512 blocks)
  gemm_bt<<<dim3(1024 / 128, ROWS / 128, 2), blk, 0, stream>>>(
      CTX, WoT, nullptr, Pwo, nullptr, ROWS, 1024, 1024, 4, 2);
  // X2 -> d_out; h2 -> Hbuf
  resid_rms_fused<<<ROWS, blk, 0, stream>>>(
      X, Pwo, Pwo + (size_t)ROWS * E_DIM, bo_sa, (float*)d_out, Hbuf);
  // gated FFN -> FF (2048 blocks)
  gemm_bt<<<dim3(2 * DFF_DIM / 128, ROWS / 128), blk, 0, stream>>>(
      Hbuf, Bcat, nullptr, FF, nullptr, ROWS, 2 * DFF_DIM, 1024, 5, 1);
  // Wout, split-K=2, atomic accumulate into d_out (512 blocks)
  gemm_bt<<<dim3(1024 / 128, ROWS / 128, 2), blk, 0, stream>>>(
      FF, WoutT, nullptr, d_out, nullptr, ROWS, 1024, 4096, 8, 2);
}

// Round 7
// 422.702 us; speedup vs baseline: 1.0763x; 1.0763x over previous
//
#include <hip/hip_runtime.h>

#define B_SZ 2
#define L_SEQ 2048
#define E_DIM 1024
#define NH 16
#define DH 64
#define DFF_DIM 4096
#define ROWS (B_SZ * L_SEQ)  // 4096
#define NCID 80              // KV chunks per (b,h): sum ceil((qt+1)/8), qt<32

typedef __attribute__((ext_vector_type(8))) short short8;
typedef __attribute__((ext_vector_type(4))) float f32x4;

// ---- bf16 <-> f32 helpers ----
__device__ __forceinline__ short f2bf(float f) {
  unsigned u = __builtin_bit_cast(unsigned, f);
  u = (u + 0x7FFFu + ((u >> 16) & 1u)) >> 16;
  return (short)u;
}
__device__ __forceinline__ float bf2f(short s) {
  unsigned u = ((unsigned)(unsigned short)s) << 16;
  return __builtin_bit_cast(float, u);
}

// ---- exact-erf GELU via A&S 7.1.26 (abs err < 1.5e-7) ----
__device__ __forceinline__ float fast_gelu(float x) {
  float ax = fabsf(x) * 0.70710678118654752f;
  float t = __builtin_amdgcn_rcpf(__builtin_fmaf(0.3275911f, ax, 1.0f));
  float p = t * __builtin_fmaf(
                    t,
                    __builtin_fmaf(
                        t,
                        __builtin_fmaf(t,
                                       __builtin_fmaf(t, 1.061405429f,
                                                      -1.453152027f),
                                       1.421413741f),
                        -0.284496736f),
                    0.254829592f);
  float erf = 1.0f - p * __expf(-ax * ax);
  erf = copysignf(erf, x);
  return 0.5f * x * (1.0f + erf);
}

// ---- async global->LDS 16B copy ----
__device__ __forceinline__ void async_copy16(const void* g, void* l) {
  __builtin_amdgcn_global_load_lds(
      (const __attribute__((address_space(1))) void*)g,
      (__attribute__((address_space(3))) void*)l, 16, 0, 0);
}

// ---- block reduction over 256 threads (4 waves) ----
__device__ __forceinline__ float block_sum256(float v) {
  __shared__ float sbuf[4];
#pragma unroll
  for (int off = 32; off > 0; off >>= 1) v += __shfl_xor(v, off, 64);
  int lane = threadIdx.x & 63, w = threadIdx.x >> 6;
  if (lane == 0) sbuf[w] = v;
  __syncthreads();
  return sbuf[0] + sbuf[1] + sbuf[2] + sbuf[3];
}

// ---- fused prep: weight transposes + rmsnorm(X) ----
// modes: 1 = plain NxK; 2/3 = Bcat 32-col interleave (Ww at +0, Wv at +32)
__global__ __launch_bounds__(256) void prep_all(
    const float* __restrict__ Wqkv, const float* __restrict__ Wo,
    const float* __restrict__ Ww, const float* __restrict__ Wv,
    const float* __restrict__ Wout, const float* __restrict__ X,
    short* __restrict__ Bqkv3, short* __restrict__ WoT,
    short* __restrict__ Bcat, short* __restrict__ WoutT,
    short* __restrict__ H) {
  __shared__ float tile[32][33];
  int b = blockIdx.x;
  if (b < 16384) {
    const float* W;
    short* Wt;
    int K, N, mode, bx, by;
    if (b < 3072) {
      W = Wqkv; Wt = Bqkv3; K = 1024; N = 3072; mode = 1;
      bx = b % 96; by = b / 96;
    } else if (b < 4096) {
      int c = b - 3072;
      W = Wo; Wt = WoT; K = 1024; N = 1024; mode = 1;
      bx = c & 31; by = c >> 5;
    } else if (b < 8192) {
      int c = b - 4096;
      W = Ww; Wt = Bcat; K = 1024; N = 4096; mode = 2;
      bx = c & 127; by = c >> 7;
    } else if (b < 12288) {
      int c = b - 8192;
      W = Wv; Wt = Bcat; K = 1024; N = 4096; mode = 3;
      bx = c & 127; by = c >> 7;
    } else {
      int c = b - 12288;
      W = Wout; Wt = WoutT; K = 4096; N = 1024; mode = 1;
      bx = c & 31; by = c >> 5;
    }
    int n0 = bx * 32, k0 = by * 32;
    int tx = threadIdx.x & 31, ty = threadIdx.x >> 5;
#pragma unroll
    for (int i = 0; i < 4; i++)
      tile[ty + 8 * i][tx] = W[(size_t)(k0 + ty + 8 * i) * N + n0 + tx];
    __syncthreads();
#pragma unroll
    for (int i = 0; i < 4; i++) {
      int n = n0 + ty + 8 * i;
      int orow = (mode == 1)
                     ? n
                     : ((n >> 5) * 64 + (n & 31) + (mode == 3 ? 32 : 0));
      Wt[(size_t)orow * K + k0 + tx] = f2bf(tile[tx][ty + 8 * i]);
    }
  } else {
    size_t row = b - 16384;
    float4 v = ((const float4*)(X + row * E_DIM))[threadIdx.x];
    float ss = v.x * v.x + v.y * v.y + v.z * v.z + v.w * v.w;
    ss = block_sum256(ss);
    float inv = rsqrtf(ss * (1.0f / E_DIM));
    short* h = H + row * E_DIM + (size_t)threadIdx.x * 4;
    h[0] = f2bf(v.x * inv);
    h[1] = f2bf(v.y * inv);
    h[2] = f2bf(v.z * inv);
    h[3] = f2bf(v.w * inv);
  }
}

// ---- fused: X1 = X + p0 + p1 + bias; X2 = X1*(1+1/rms) -> Xout; h2 -> H ----
__global__ __launch_bounds__(256) void resid_rms_fused(
    const float* __restrict__ X, const float* __restrict__ P0,
    const float* __restrict__ P1, const float* __restrict__ bias,
    float* __restrict__ Xout, short* __restrict__ H) {
  size_t row = blockIdx.x;
  int t = threadIdx.x;
  float4 v = ((const float4*)(X + row * E_DIM))[t];
  float4 a = ((const float4*)(P0 + row * E_DIM))[t];
  float4 b = ((const float4*)(P1 + row * E_DIM))[t];
  float4 c = ((const float4*)bias)[t];
  v.x += a.x + b.x + c.x;
  v.y += a.y + b.y + c.y;
  v.z += a.z + b.z + c.z;
  v.w += a.w + b.w + c.w;
  float ss = v.x * v.x + v.y * v.y + v.z * v.z + v.w * v.w;
  ss = block_sum256(ss);
  float inv = rsqrtf(ss * (1.0f / E_DIM));
  float4 o;
  o.x = v.x * (1.0f + inv);
  o.y = v.y * (1.0f + inv);
  o.z = v.z * (1.0f + inv);
  o.w = v.w * (1.0f + inv);
  ((float4*)(Xout + row * E_DIM))[t] = o;
  short* h = H + row * E_DIM + (size_t)t * 4;
  h[0] = f2bf(v.x * inv);
  h[1] = f2bf(v.y * inv);
  h[2] = f2bf(v.z * inv);
  h[3] = f2bf(v.w * inv);
}

// ---- out += p0 + p1 (in place on d_out, which holds X2) ----
__global__ __launch_bounds__(256) void add2_k(const float* __restrict__ P0,
                                              const float* __restrict__ P1,
                                              float* __restrict__ out) {
  size_t i = (size_t)blockIdx.x * 256 + threadIdx.x;
  float4 v = ((const float4*)out)[i];
  float4 a = ((const float4*)P0)[i];
  float4 b = ((const float4*)P1)[i];
  v.x += a.x + b.x;
  v.y += a.y + b.y;
  v.z += a.z + b.z;
  v.w += a.w + b.w;
  ((float4*)out)[i] = v;
}

// ---- GEMM: C(MxN) = A(MxK bf16) @ Bt(NxK bf16)^T, BK=64 twin buffers ----
// epi: 4 = f32 partial (split-K via z), 5 = gated-FFN (Bcat 32-interleaved;
// each wave holds w in ni 0-1 and v in ni 2-3 for the same ff cols),
// 6 = QKV 3-way scatter (out=Qh, out2=Kh, out3=Vh, bias=bqkv)
__global__ __launch_bounds__(256, 2) void gemm_bt(
    const short* __restrict__ A, const short* __restrict__ Bt,
    const float* __restrict__ bias, void* __restrict__ out,
    void* __restrict__ out2, void* __restrict__ out3, int M, int N, int K,
    int epi, int ksplit) {
  __shared__ short smem[128 * 32 * 4];  // As0 Bs0 As1 Bs1 = 32 KB
  short* As0 = smem;
  short* Bs0 = smem + 4096;
  short* As1 = smem + 8192;
  short* Bs1 = smem + 12288;
  int t = threadIdx.x;
  int lane = t & 63;
  int quad = lane >> 4, l16 = lane & 15;
  int wave = t >> 6;
  int wr = wave >> 1, wc = wave & 1;
  int m0 = blockIdx.y * 128, n0 = blockIdx.x * 128;
  int klen = K / ksplit;
  int kstart = blockIdx.z * klen;

  f32x4 acc[4][4];
#pragma unroll
  for (int i = 0; i < 4; i++)
#pragma unroll
    for (int j = 0; j < 4; j++) acc[i][j] = (f32x4){0.f, 0.f, 0.f, 0.f};

  for (int k0 = kstart; k0 < kstart + klen; k0 += 64) {
    __syncthreads();
#pragma unroll
    for (int p = 0; p < 2; p++) {
      int s = p * 256 + t;
      int mm = s >> 2, kk = (s & 3) * 8;
      const short* ag = A + (size_t)(m0 + mm) * K + k0 + kk;
      const short* bg = Bt + (size_t)(n0 + mm) * K + k0 + kk;
      async_copy16(ag, As0 + (size_t)s * 8);
      async_copy16(bg, Bs0 + (size_t)s * 8);
      async_copy16(ag + 32, As1 + (size_t)s * 8);
      async_copy16(bg + 32, Bs1 + (size_t)s * 8);
    }
    __syncthreads();
#pragma unroll
    for (int half = 0; half < 2; half++) {
      const short* As = half ? As1 : As0;
      const short* Bs = half ? Bs1 : Bs0;
      short8 af[4], bfv[4];
#pragma unroll
      for (int i = 0; i < 4; i++) {
        af[i] = *(const short8*)&As[(wr * 64 + i * 16 + l16) * 32 + quad * 8];
        bfv[i] = *(const short8*)&Bs[(wc * 64 + i * 16 + l16) * 32 + quad * 8];
      }
#pragma unroll
      for (int mi = 0; mi < 4; mi++)
#pragma unroll
        for (int ni = 0; ni < 4; ni++)
          acc[mi][ni] = __builtin_amdgcn_mfma_f32_16x16x32_bf16(
              af[mi], bfv[ni], acc[mi][ni], 0, 0, 0);
    }
  }

  if (epi == 5) {
    // gated FFN, fully wave-local: ffcol = bx*64 + wc*32 + ni*16 + l16
    short* FF = (short*)out;
    int ffbase = blockIdx.x * 64 + wc * 32;
#pragma unroll
    for (int mi = 0; mi < 4; mi++)
#pragma unroll
      for (int ni = 0; ni < 2; ni++)
#pragma unroll
        for (int r = 0; r < 4; r++) {
          int rowl = wr * 64 + mi * 16 + quad * 4 + r;
          float g = fast_gelu(acc[mi][ni][r]);
          FF[(size_t)(m0 + rowl) * DFF_DIM + ffbase + ni * 16 + l16] =
              f2bf(g * acc[mi][ni + 2][r]);
        }
    return;
  }

#pragma unroll
  for (int mi = 0; mi < 4; mi++) {
#pragma unroll
    for (int ni = 0; ni < 4; ni++) {
      int col = n0 + wc * 64 + ni * 16 + l16;
#pragma unroll
      for (int r = 0; r < 4; r++) {
        int row = m0 + wr * 64 + mi * 16 + quad * 4 + r;
        float v = acc[mi][ni][r];
        if (epi == 4) {
          float* po = (float*)out + (size_t)blockIdx.z * ((size_t)M * N);
          po[(size_t)row * N + col] = v;
        } else {  // epi == 6: col = h*192 + ty*64 + d
          v += bias[col];
          int h = col / 192;
          int rem = col - h * 192;
          int ty = rem >> 6, d = rem & 63;
          short* dst = (ty == 0) ? (short*)out
                                 : ((ty == 1) ? (short*)out2 : (short*)out3);
          int bb = row >> 11, l = row & 2047;
          dst[((size_t)(bb * NH + h) * L_SEQ + l) * DH + d] = f2bf(v);
        }
      }
    }
  }
}

// ---- V transpose: Vh[bh][l][d] -> VTh[bh][d][l] ----
__global__ __launch_bounds__(256) void v_transp(const short* __restrict__ Vh,
                                                short* __restrict__ VTh) {
  int lt = blockIdx.x, bh = blockIdx.y;
  __shared__ short vtile[64 * 72];
  int t = threadIdx.x;
  int r = t >> 3, c = (t & 7) * 8;
  const short* src = Vh + ((size_t)bh * L_SEQ + lt * 64) * DH;
#pragma unroll
  for (int p = 0; p < 2; p++) {
    int row = r + p * 32;
    short8 vv = *(const short8*)(src + (size_t)row * DH + c);
    *(short8*)&vtile[row * 72 + c] = vv;
  }
  __syncthreads();
#pragma unroll
  for (int p = 0; p < 2; p++) {
    int d = r + p * 32;
    short8 o;
#pragma unroll
    for (int u = 0; u < 8; u++) o[u] = vtile[(c + u) * 72 + d];
    *(short8*)(VTh + ((size_t)bh * DH + d) * L_SEQ + lt * 64 + c) = o;
  }
}

// ---- flash attention, constant-m softmax, split-KV (8-tile chunks) ----
__global__ __launch_bounds__(256) void attn_k(const short* __restrict__ Qh,
                                              const short* __restrict__ Kh,
                                              const short* __restrict__ VTh,
                                              float* __restrict__ OP,
                                              float* __restrict__ RS) {
  int cid = blockIdx.x;
  int bh = blockIdx.y;
  int b = bh >> 4, h = bh & 15;
  int qt, ch;
  if (cid < 8) {
    qt = cid; ch = 0;
  } else if (cid < 24) {
    qt = 8 + ((cid - 8) >> 1); ch = (cid - 8) & 1;
  } else if (cid < 48) {
    qt = 16 + (cid - 24) / 3; ch = (cid - 24) % 3;
  } else {
    qt = 24 + ((cid - 48) >> 2); ch = (cid - 48) & 3;
  }
  int t0 = ch * 8;
  int tend = min(t0 + 8, qt + 1);

  int t = threadIdx.x;
  int wave = t >> 6, lane = t & 63;
  int quad = lane >> 4, l16 = lane & 15;

  __shared__ short kt[64 * 72];
  __shared__ short vt[64 * 72];
  __shared__ short pb[4 * 16 * 70];

  const float slope = exp2f(-(1.0f + (7.0f / 15.0f) * (float)h));
  int iw = qt * 64 + wave * 16;

  short8 qf[2];
  {
    const short* qp = Qh + ((size_t)bh * L_SEQ + iw + l16) * DH + quad * 8;
    qf[0] = *(const short8*)(qp);
    qf[1] = *(const short8*)(qp + 32);
  }

  f32x4 o[4];
#pragma unroll
  for (int i = 0; i < 4; i++) o[i] = (f32x4){0.f, 0.f, 0.f, 0.f};
  float rs[4] = {0.f, 0.f, 0.f, 0.f};
  float crow[4];
  int irow[4];
#pragma unroll
  for (int r = 0; r < 4; r++) {
    irow[r] = iw + quad * 4 + r;
    crow[r] = -slope * (float)irow[r] - 8.0f;
  }

  int sr = t >> 3, sc = (t & 7) * 8;
  const short* kg = Kh + (size_t)bh * L_SEQ * DH;
  const short* vg = VTh + (size_t)bh * DH * L_SEQ;
  short8 kreg[2], vreg[2];
  auto loadKV = [&](int j0) {
    kreg[0] = *(const short8*)(kg + (size_t)(j0 + sr) * DH + sc);
    kreg[1] = *(const short8*)(kg + (size_t)(j0 + sr + 32) * DH + sc);
    vreg[0] = *(const short8*)(vg + (size_t)sr * L_SEQ + j0 + sc);
    vreg[1] = *(const short8*)(vg + (size_t)(sr + 32) * L_SEQ + j0 + sc);
  };
  loadKV(t0 * 64);

  short* pw = &pb[wave * 16 * 70];
  for (int tix = t0; tix < tend; ++tix) {
    int j0 = tix * 64;
    __syncthreads();
    *(short8*)&kt[sr * 72 + sc] = kreg[0];
    *(short8*)&kt[(sr + 32) * 72 + sc] = kreg[1];
    *(short8*)&vt[sr * 72 + sc] = vreg[0];
    *(short8*)&vt[(sr + 32) * 72 + sc] = vreg[1];
    __syncthreads();
    if (tix + 1 < tend) loadKV(j0 + 64);

    f32x4 s[4];
#pragma unroll
    for (int nt = 0; nt < 4; nt++) {
      f32x4 a = (f32x4){0.f, 0.f, 0.f, 0.f};
#pragma unroll
      for (int ks = 0; ks < 2; ks++) {
        short8 bf =
            *(const short8*)&kt[(nt * 16 + l16) * 72 + ks * 32 + quad * 8];
        a = __builtin_amdgcn_mfma_f32_16x16x32_bf16(qf[ks], bf, a, 0, 0, 0);
      }
      s[nt] = a;
    }
    bool diag = (tix == qt);
#pragma unroll
    for (int nt = 0; nt < 4; nt++) {
      int j = j0 + nt * 16 + l16;
      float jb = slope * (float)j;
#pragma unroll
      for (int r = 0; r < 4; r++) {
        float v = __builtin_fmaf(s[nt][r], 0.125f, jb + crow[r]);
        if (diag && j > irow[r]) v = -1e30f;
        float p = __expf(v);
        rs[r] += p;
        pw[(quad * 4 + r) * 70 + nt * 16 + l16] = f2bf(p);
      }
    }
    short8 pf[2];
    pf[0] = *(const short8*)&pw[l16 * 70 + quad * 8];
    pf[1] = *(const short8*)&pw[l16 * 70 + 32 + quad * 8];
#pragma unroll
    for (int nt = 0; nt < 4; nt++) {
#pragma unroll
      for (int ks = 0; ks < 2; ks++) {
        short8 bv =
            *(const short8*)&vt[(nt * 16 + l16) * 72 + ks * 32 + quad * 8];
        o[nt] = __builtin_amdgcn_mfma_f32_16x16x32_bf16(pf[ks], bv, o[nt], 0,
                                                        0, 0);
      }
    }
  }
  float* op = OP + ((size_t)bh * NCID + cid) * 64 * 64;
  float* rsp = RS + ((size_t)bh * NCID + cid) * 64;
#pragma unroll
  for (int r = 0; r < 4; r++) {
#pragma unroll
    for (int off = 1; off < 16; off <<= 1) rs[r] += __shfl_xor(rs[r], off, 64);
    int rowl = wave * 16 + quad * 4 + r;
#pragma unroll
    for (int nt = 0; nt < 4; nt++) op[rowl * 64 + nt * 16 + l16] = o[nt][r];
    if (l16 == 0) rsp[rowl] = rs[r];
  }
}

// ---- merge split-KV partials: ctx = sum(O) / sum(l) -> bf16 ----
__global__ __launch_bounds__(256) void attn_merge(const float* __restrict__ OP,
                                                  const float* __restrict__ RS,
                                                  short* __restrict__ ctx) {
  int row = blockIdx.x;
  int b = row >> 11, i = row & 2047;
  int qt = i >> 6, rowin = i & 63;
  int base, nch;
  if (qt < 8) {
    base = qt; nch = 1;
  } else if (qt < 16) {
    base = 8 + 2 * (qt - 8); nch = 2;
  } else if (qt < 24) {
    base = 24 + 3 * (qt - 16); nch = 3;
  } else {
    base = 48 + 4 * (qt - 24); nch = 4;
  }
  int t = threadIdx.x;
  int col = t * 4;
  int h = col >> 6;
  int bh = b * NH + h;
  float4 o = {0.f, 0.f, 0.f, 0.f};
  float l = 0.f;
  for (int s = 0; s < nch; s++) {
    size_t cb = ((size_t)bh * NCID + base + s) * 64 + rowin;
    float4 v = *(const float4*)&OP[cb * 64 + (col & 63)];
    o.x += v.x;
    o.y += v.y;
    o.z += v.z;
    o.w += v.w;
    l += RS[cb];
  }
  float inv = 1.0f / l;
  short* dst = ctx + (size_t)row * (NH * DH) + col;
  dst[0] = f2bf(o.x * inv);
  dst[1] = f2bf(o.y * inv);
  dst[2] = f2bf(o.z * inv);
  dst[3] = f2bf(o.w * inv);
}

extern "C" void kernel_launch(void* const* d_in, const int* in_sizes, int n_in,
                              void* d_out, int out_size, void* d_ws,
                              size_t ws_size, hipStream_t stream) {
  const float* X = (const float*)d_in[0];
  const float* Wqkv = (const float*)d_in[2];
  const float* bqkv = (const float*)d_in[3];
  const float* Wo_sa = (const float*)d_in[4];
  const float* bo_sa = (const float*)d_in[5];
  const float* Ww = (const float*)d_in[12];
  const float* Wv = (const float*)d_in[13];
  const float* Wout = (const float*)d_in[14];

  char* ws = (char*)d_ws;
  auto take = [&](size_t bytes) {
    char* p = ws;
    ws += (bytes + 255) & ~(size_t)255;
    return p;
  };
  short* Bqkv3 = (short*)take((size_t)3072 * 1024 * 2);         // 6 MB
  short* WoT = (short*)take((size_t)E_DIM * E_DIM * 2);         // 2 MB
  short* Bcat = (short*)take((size_t)2 * DFF_DIM * E_DIM * 2);  // 16 MB
  short* WoutT = (short*)take((size_t)E_DIM * DFF_DIM * 2);     // 8 MB
  short* Hbuf = (short*)take((size_t)ROWS * E_DIM * 2);         // 8 MB
  short* Qh = (short*)take((size_t)ROWS * NH * DH * 2);         // 8 MB
  short* Kh = (short*)take((size_t)ROWS * NH * DH * 2);         // 8 MB
  short* Vh = (short*)take((size_t)ROWS * NH * DH * 2);         // 8 MB
  short* VTh = (short*)take((size_t)ROWS * NH * DH * 2);        // 8 MB
  short* CTX = (short*)take((size_t)ROWS * NH * DH * 2);        // 8 MB
  char* big = take((size_t)48 * 1024 * 1024);                   // 48 MB
  // OP (41.9 MB) + RS (0.66 MB) in big[0:42.6]; dead after attn_merge.
  float* OP = (float*)big;
  float* RS = OP + (size_t)B_SZ * NH * NCID * 64 * 64;
  // Pwo (32 MB) then FF (32 MB) reuse big[16:48]:
  float* Pwo = (float*)(big + (size_t)16 * 1024 * 1024);
  short* FF = (short*)Pwo;
  // Wout partials (32 MB) span the dead Qh..VTh region:
  float* Pwout = (float*)Qh;
  (void)ws_size;
  (void)in_sizes;
  (void)n_in;
  (void)out_size;

  dim3 blk(256);
  prep_all<<<16384 + ROWS, blk, 0, stream>>>(Wqkv, Wo_sa, Ww, Wv, Wout, X,
                                             Bqkv3, WoT, Bcat, WoutT, Hbuf);
  // QKV gemm, 3-way head-major scatter (768 blocks)
  gemm_bt<<<dim3(3072 / 128, ROWS / 128), blk, 0, stream>>>(
      Hbuf, Bqkv3, bqkv, Qh, Kh, Vh, ROWS, 3072, 1024, 6, 1);
  v_transp<<<dim3(L_SEQ / 64, B_SZ * NH), blk, 0, stream>>>(Vh, VTh);
  attn_k<<<dim3(NCID, B_SZ * NH), blk, 0, stream>>>(Qh, Kh, VTh, OP, RS);
  attn_merge<<<ROWS, blk, 0, stream>>>(OP, RS, CTX);
  // Wo partials, split-K=2 (512 blocks)
  gemm_bt<<<dim3(1024 / 128, ROWS / 128, 2), blk, 0, stream>>>(
      CTX, WoT, nullptr, Pwo, nullptr, nullptr, ROWS, 1024, 1024, 4, 2);
  // X2 -> d_out; h2 -> Hbuf
  resid_rms_fused<<<ROWS, blk, 0, stream>>>(
      X, Pwo, Pwo + (size_t)ROWS * E_DIM, bo_sa, (float*)d_out, Hbuf);
  // gated FFN -> FF (2048 blocks, wave-local epilogue)
  gemm_bt<<<dim3(2 * DFF_DIM / 128, ROWS / 128), blk, 0, stream>>>(
      Hbuf, Bcat, nullptr, FF, nullptr, nullptr, ROWS, 2 * DFF_DIM, 1024, 5,
      1);
  // Wout partials, split-K=2 (512 blocks)
  gemm_bt<<<dim3(1024 / 128, ROWS / 128, 2), blk, 0, stream>>>(
      FF, WoutT, nullptr, Pwout, nullptr, nullptr, ROWS, 1024, 4096, 4, 2);
  // d_out += p0 + p1
  add2_k<<<ROWS * E_DIM / (256 * 4), blk, 0, stream>>>(
      Pwout, Pwout + (size_t)ROWS * E_DIM, (float*)d_out);
}